// Round 5
// baseline (374.780 us; speedup 1.0000x reference)
//
#include <hip/hip_runtime.h>
#include <hip/hip_bf16.h>

typedef __attribute__((ext_vector_type(8))) __bf16 bf16x8;
typedef __attribute__((ext_vector_type(4))) float f32x4;

#define ALPHA 0.999f
#define THETA 0.05f

#define K1_BLOCKS 2048
#define WPB 4
// One wave-private record per row, 68 halfs (136 B, b64-aligned; 34-dword
// stride -> staging writes 4-way bank aliased (cheap), frag reads 2-way (free)).
// Layout: dy@0(16) | q@16(16) | h@32(32) | pad@64(4).  Phase B: dh overlays
// [0..32) after q-fragments have been pre-read into registers.
#define RREC 68
#define A_DY 0
#define A_Q  16
#define A_H  32
#define B_DH 0
#define WAVE_LDS_HALFS (64*RREC)          // 4352 halfs = 8704 B per wave
#define SMEM_HALFS (WPB*WAVE_LDS_HALFS)   // 34816 B >= 28672 B reduction region

__device__ __forceinline__ float sigmoidf_(float z){ return 1.f/(1.f+__expf(-z)); }

__device__ __forceinline__ unsigned pk2_(float a, float b){
  union { __bf16 h[2]; unsigned u; } x; x.h[0]=(__bf16)a; x.h[1]=(__bf16)b; return x.u;
}
// unpack bf16 pair (low/high) back to f32
__device__ __forceinline__ float upk_lo_(unsigned u){ return __uint_as_float(u << 16); }
__device__ __forceinline__ float upk_hi_(unsigned u){ return __uint_as_float(u & 0xffff0000u); }

// ---------------- Kernel 1: gradient pass -> per-block partial sums ----------------
// NOTE: no 2nd __launch_bounds__ arg. Measured occupancy tracked that arg
// exactly in R1-R4 (it pins waves/EU); residency must come from LDS+VGPR.
__global__ __launch_bounds__(256)
void k1_grad(const float* __restrict__ X,
             const float* __restrict__ W0, const float* __restrict__ b0,
             const float* __restrict__ W1, const float* __restrict__ b1,
             const float* __restrict__ WV, const float* __restrict__ WQ,
             float* __restrict__ wsPart, int N)
{
  __shared__ __align__(16) __bf16 smem[SMEM_HALFS];
  const int tid = threadIdx.x;
  const int w = tid >> 6, l = tid & 63;
  __bf16* WB = smem + w*WAVE_LDS_HALFS;

  bf16x8 ones;
  #pragma unroll
  for (int i=0;i<8;++i) ones[i] = (__bf16)1.f;

  f32x4 acc[7] = {};

  const int nb = N >> 6;                 // 64-row batches
  const int tw = K1_BLOCKS*WPB;          // total waves
  const int gw = blockIdx.x*WPB + w;
  const int iters = (nb + tw - 1) / tw;

  for (int it = 0; it < iters; ++it) {
    const int batch = gw + it*tw;
    const bool active = (batch < nb);

    if (active) {
      const int row = (batch<<6) + l;
      const float* xp = X + (size_t)row*16;
      float x[16];
      {
        const float4* xv = (const float4*)xp;
        float4 t0=xv[0], t1=xv[1], t2=xv[2], t3=xv[3];
        x[0]=t0.x; x[1]=t0.y; x[2]=t0.z; x[3]=t0.w;
        x[4]=t1.x; x[5]=t1.y; x[6]=t1.z; x[7]=t1.w;
        x[8]=t2.x; x[9]=t2.y; x[10]=t2.z; x[11]=t2.w;
        x[12]=t3.x; x[13]=t3.y; x[14]=t3.z; x[15]=t3.w;
      }

      __bf16* R = WB + l*RREC;

      // q = l2norm(silu(x @ WQ^T))  -- computed first, staged early
      float q[16]; float n2 = 0.f;
      #pragma unroll
      for (int k=0;k<16;++k){
        float s = 0.f;
        #pragma unroll
        for (int d=0;d<16;++d) s = fmaf(x[d], WQ[k*16+d], s);
        float t = s * sigmoidf_(s);
        q[k] = t; n2 = fmaf(t, t, n2);
      }
      const float inv = 1.f / fmaxf(sqrtf(n2), 1e-12f);
      #pragma unroll
      for (int k=0;k<16;++k) q[k] *= inv;
      {
        uint2* p = (uint2*)(R + A_Q);
        #pragma unroll
        for (int k=0;k<16;k+=4) p[k>>2] = make_uint2(pk2_(q[k],q[k+1]), pk2_(q[k+2],q[k+3]));
      }

      // vv = silu(x @ WV^T), packed bf16 pairs (x dies here)
      unsigned vvp[8];
      #pragma unroll
      for (int k=0;k<16;k+=2){
        float s0v = 0.f, s1v = 0.f;
        #pragma unroll
        for (int d=0;d<16;++d){
          s0v = fmaf(x[d], WV[k*16+d],     s0v);
          s1v = fmaf(x[d], WV[(k+1)*16+d], s1v);
        }
        vvp[k>>1] = pk2_(s0v * sigmoidf_(s0v), s1v * sigmoidf_(s1v));
      }

      // h = silu(q @ W0^T + b0); dsilu packed bf16 pairs (q dies here)
      float h[32]; unsigned dshp[16];
      #pragma unroll
      for (int j=0;j<32;j+=2){
        float sa = b0[j], sb = b0[j+1];
        #pragma unroll
        for (int d=0;d<16;++d){
          sa = fmaf(q[d], W0[j*16+d],     sa);
          sb = fmaf(q[d], W0[(j+1)*16+d], sb);
        }
        float sga = sigmoidf_(sa), sgb = sigmoidf_(sb);
        h[j]   = sa*sga;
        h[j+1] = sb*sgb;
        dshp[j>>1] = pk2_(sga * fmaf(sa, 1.f - sga, 1.f),
                          sgb * fmaf(sb, 1.f - sgb, 1.f));
      }
      // stage h (regs stay live for y matvec)
      {
        uint2* p = (uint2*)(R + A_H);
        #pragma unroll
        for (int j=0;j<32;j+=4) p[j>>2] = make_uint2(pk2_(h[j],h[j+1]), pk2_(h[j+2],h[j+3]));
      }

      // y, dy (unscaled; scale applied in k2b). h, vv die here.
      float dy[16];
      #pragma unroll
      for (int k=0;k<16;++k){
        float s = b1[k];
        #pragma unroll
        for (int j=0;j<32;++j) s = fmaf(h[j], W1[k*32+j], s);
        float sg = sigmoidf_(s);
        float y = s*sg;
        float ds = sg * fmaf(s, 1.f - sg, 1.f);
        float vvk = (k&1) ? upk_hi_(vvp[k>>1]) : upk_lo_(vvp[k>>1]);
        dy[k] = (y - vvk) * ds;
      }
      {
        uint2* p = (uint2*)(R + A_DY);
        #pragma unroll
        for (int k=0;k<16;k+=4) p[k>>2] = make_uint2(pk2_(dy[k],dy[k+1]), pk2_(dy[k+2],dy[k+3]));
      }

      // ---- Phase A: gW1 / gb1 MFMAs ----
      const int c = l & 15;
      #pragma unroll
      for (int kc=0;kc<2;++kc){
        const int r0 = (kc<<5) + ((l>>4)<<3);
        const __bf16* base = WB + r0*RREC + c;
        bf16x8 fdy, fh0, fh1;
        #pragma unroll
        for (int i=0;i<8;++i){
          const __bf16* pr = base + i*RREC;
          fdy[i] = pr[A_DY];
          fh0[i] = pr[A_H];
          fh1[i] = pr[A_H + 16];
        }
        acc[0] = __builtin_amdgcn_mfma_f32_16x16x32_bf16(fdy, fh0, acc[0], 0,0,0); // gW1[:, 0:16]
        acc[1] = __builtin_amdgcn_mfma_f32_16x16x32_bf16(fdy, fh1, acc[1], 0,0,0); // gW1[:,16:32]
        acc[2] = __builtin_amdgcn_mfma_f32_16x16x32_bf16(fdy, ones, acc[2], 0,0,0); // gb1
      }

      // pre-read q fragments (before dh staging overwrites [0..32))
      bf16x8 fq[2];
      #pragma unroll
      for (int kc=0;kc<2;++kc){
        const int r0 = (kc<<5) + ((l>>4)<<3);
        const __bf16* base = WB + r0*RREC + c;
        #pragma unroll
        for (int i=0;i<8;++i) fq[kc][i] = base[i*RREC + A_Q];
      }

      // dh = (dy @ W1) * dsilu (dy dies here)
      float dh[32];
      #pragma unroll
      for (int j=0;j<32;++j){
        float s = 0.f;
        #pragma unroll
        for (int k=0;k<16;++k) s = fmaf(dy[k], W1[k*32+j], s);
        float dsj = (j&1) ? upk_hi_(dshp[j>>1]) : upk_lo_(dshp[j>>1]);
        dh[j] = s * dsj;
      }
      {
        uint2* p = (uint2*)(R + B_DH);
        #pragma unroll
        for (int j=0;j<32;j+=4) p[j>>2] = make_uint2(pk2_(dh[j],dh[j+1]), pk2_(dh[j+2],dh[j+3]));
      }

      // ---- Phase B: gW0 / gb0 MFMAs ----
      #pragma unroll
      for (int kc=0;kc<2;++kc){
        const int r0 = (kc<<5) + ((l>>4)<<3);
        const __bf16* base = WB + r0*RREC + c;
        bf16x8 fd0, fd1;
        #pragma unroll
        for (int i=0;i<8;++i){
          const __bf16* pr = base + i*RREC;
          fd0[i] = pr[B_DH];
          fd1[i] = pr[B_DH + 16];
        }
        acc[3] = __builtin_amdgcn_mfma_f32_16x16x32_bf16(fd0, fq[kc], acc[3], 0,0,0); // gW0[0:16, :]
        acc[4] = __builtin_amdgcn_mfma_f32_16x16x32_bf16(fd1, fq[kc], acc[4], 0,0,0); // gW0[16:32,:]
        acc[5] = __builtin_amdgcn_mfma_f32_16x16x32_bf16(fd0, ones, acc[5], 0,0,0);   // gb0[0:16]
        acc[6] = __builtin_amdgcn_mfma_f32_16x16x32_bf16(fd1, ones, acc[6], 0,0,0);   // gb0[16:32]
      }
    }
  }

  // block reduction over the 4 waves (reuse LDS as float; 4*1792*4B = 28672 B)
  __syncthreads();
  float* red = (float*)smem;
  #pragma unroll
  for (int a=0;a<7;++a){
    #pragma unroll
    for (int r=0;r<4;++r)
      red[w*1792 + a*256 + l*4 + r] = acc[a][r];
  }
  __syncthreads();
  for (int s = tid; s < 1792; s += 256){
    float sum = red[s] + red[1792+s] + red[2*1792+s] + red[3*1792+s];
    wsPart[(size_t)blockIdx.x*1792 + s] = sum;
  }
}

// ---------------- Kernel 2a: partial reduce (2048 -> 16 chunks) ----------------
__global__ void k2a_reduce(const float* __restrict__ wsPart, float* __restrict__ tmp)
{
  const int s = blockIdx.x*256 + threadIdx.x;   // 0..1791 (grid.x = 7)
  const int c = blockIdx.y;                     // 0..15
  float g = 0.f;
  #pragma unroll 8
  for (int j=0;j<128;++j) g += wsPart[(size_t)(c*128+j)*1792 + s];
  tmp[(size_t)c*1792 + s] = g;
}

// ---------------- Kernel 2b: final reduce, form updated params ----------------
__global__ void k2b_reduce(const float* __restrict__ tmp,
                           const float* __restrict__ W0, const float* __restrict__ b0,
                           const float* __restrict__ W1, const float* __restrict__ b1,
                           float* __restrict__ P, float scale)
{
  int s = blockIdx.x*256 + threadIdx.x;
  if (s >= 1792) return;
  float g = 0.f;
  #pragma unroll
  for (int c=0;c<16;++c) g += tmp[(size_t)c*1792 + s];
  g *= scale;   // 2/(N*16)
  int a = s >> 8, l = (s >> 2) & 63, r = s & 3;
  int m = ((l>>4)<<2) + r, n = l & 15;
  // P layout (floats): W0[0..511], b0[512..543], W1[544..1055], b1[1056..1071]
  if (a==0)      P[544 + m*32 + n]       = ALPHA*W1[m*32+n]        - THETA*g;
  else if (a==1) P[544 + m*32 + 16 + n]  = ALPHA*W1[m*32+16+n]     - THETA*g;
  else if (a==2){ if (n==0) P[1056 + m]  = ALPHA*b1[m]             - THETA*g; }
  else if (a==3) P[m*16 + n]             = ALPHA*W0[m*16+n]        - THETA*g;
  else if (a==4) P[(16+m)*16 + n]        = ALPHA*W0[(16+m)*16+n]   - THETA*g;
  else if (a==5){ if (n==0) P[512 + m]   = ALPHA*b0[m]             - THETA*g; }
  else           { if (n==0) P[512+16+m] = ALPHA*b0[16+m]          - THETA*g; }
}

// ---------------- Kernel 3: retrieve pass ----------------
__global__ __launch_bounds__(256)
void k3_retrieve(const float* __restrict__ X, const float* __restrict__ WQ,
                 const float* __restrict__ P, float* __restrict__ out, int N)
{
  int row = blockIdx.x*256 + threadIdx.x;
  if (row >= N) return;
  const float* xp = X + (size_t)row*16;
  float x[16];
  {
    const float4* xv = (const float4*)xp;
    float4 t0=xv[0], t1=xv[1], t2=xv[2], t3=xv[3];
    x[0]=t0.x; x[1]=t0.y; x[2]=t0.z; x[3]=t0.w;
    x[4]=t1.x; x[5]=t1.y; x[6]=t1.z; x[7]=t1.w;
    x[8]=t2.x; x[9]=t2.y; x[10]=t2.z; x[11]=t2.w;
    x[12]=t3.x; x[13]=t3.y; x[14]=t3.z; x[15]=t3.w;
  }
  // r = silu(l2norm(x @ WQ^T))   (note: norm BEFORE silu here)
  float rq[16]; float n2 = 0.f;
  #pragma unroll
  for (int k=0;k<16;++k){
    float s = 0.f;
    #pragma unroll
    for (int d=0;d<16;++d) s = fmaf(x[d], WQ[k*16+d], s);
    rq[k] = s; n2 = fmaf(s, s, n2);
  }
  const float inv = 1.f / fmaxf(sqrtf(n2), 1e-12f);
  #pragma unroll
  for (int k=0;k<16;++k){
    float z = rq[k]*inv;
    rq[k] = z * sigmoidf_(z);
  }
  // h = silu(r @ W0'^T + b0')
  float h[32];
  #pragma unroll
  for (int j=0;j<32;++j){
    float s = P[512+j];
    #pragma unroll
    for (int d=0;d<16;++d) s = fmaf(rq[d], P[j*16+d], s);
    h[j] = s * sigmoidf_(s);
  }
  // o = silu(h @ W1'^T + b1')
  float o[16];
  #pragma unroll
  for (int k=0;k<16;++k){
    float s = P[1056+k];
    #pragma unroll
    for (int j=0;j<32;++j) s = fmaf(h[j], P[544 + k*32 + j], s);
    o[k] = s * sigmoidf_(s);
  }
  float4* op = (float4*)(out + (size_t)row*16);
  op[0] = make_float4(o[0],o[1],o[2],o[3]);
  op[1] = make_float4(o[4],o[5],o[6],o[7]);
  op[2] = make_float4(o[8],o[9],o[10],o[11]);
  op[3] = make_float4(o[12],o[13],o[14],o[15]);
}

extern "C" void kernel_launch(void* const* d_in, const int* in_sizes, int n_in,
                              void* d_out, int out_size, void* d_ws, size_t ws_size,
                              hipStream_t stream)
{
  const float* X  = (const float*)d_in[0];
  const float* W0 = (const float*)d_in[1];
  const float* b0 = (const float*)d_in[2];
  const float* W1 = (const float*)d_in[3];
  const float* b1 = (const float*)d_in[4];
  const float* WV = (const float*)d_in[6];
  const float* WQ = (const float*)d_in[7];
  float* ws   = (float*)d_ws;
  float* P    = ws;                         // 1072 floats of updated params
  float* part = ws + 2048;                  // 2048*1792 floats of partials
  float* tmp  = part + (size_t)K1_BLOCKS*1792;  // 16*1792 floats

  const int N = in_sizes[0] / 16;
  const float scale = 2.f / (16.f * (float)N);

  k1_grad<<<dim3(K1_BLOCKS), dim3(256), 0, stream>>>(X, W0, b0, W1, b1, WV, WQ, part, N);
  k2a_reduce<<<dim3(7,16), dim3(256), 0, stream>>>(part, tmp);
  k2b_reduce<<<dim3(7), dim3(256), 0, stream>>>(tmp, W0, b0, W1, b1, P, scale);
  k3_retrieve<<<dim3((N+255)/256), dim3(256), 0, stream>>>(X, WQ, P, (float*)d_out, N);
}

// Round 6
// 233.710 us; speedup vs baseline: 1.6036x; 1.6036x over previous
//
#include <hip/hip_runtime.h>
#include <hip/hip_bf16.h>

typedef __attribute__((ext_vector_type(8))) __bf16 bf16x8;
typedef __attribute__((ext_vector_type(4))) float f32x4;

#define ALPHA 0.999f
#define THETA 0.05f

#define K1_BLOCKS 512
#define K1_WAVES 16
// Per-wave region: 32 rows x 50 halfs (3200 B). 50-half stride (25 dwords,
// gcd(25,32)=1) proven 0-conflict in R1-R5. Phase A: dy@0(16) | h@16(32).
// Phase B overlays: dh@0(32) | q@32(16). Each 64-row batch is staged in two
// 32-row sub-phases (lanes 0-31 then 32-63) so 16 waves fit in 51.2 KB.
#define RREC 50
#define F_DY 0
#define F_H  16
#define F_DH 0
#define F_Q  32
#define WAVE_REGION_HALFS (32*RREC)       // 1600 halfs = 3200 B
#define SMEM_BYTES 57344                  // max(16*3200=51200, 8*1792*4=57344)

__device__ __forceinline__ float sigmoidf_(float z){ return 1.f/(1.f+__expf(-z)); }

__device__ __forceinline__ unsigned pk2_(float a, float b){
  union { __bf16 h[2]; unsigned u; } x; x.h[0]=(__bf16)a; x.h[1]=(__bf16)b; return x.u;
}

// ---------------- Kernel 1: gradient pass -> per-block partial sums ----------------
// 1024-thread block, NO 2nd launch_bounds arg: measured across R1-R5, the 2nd
// arg pins resident waves/EU (default 1) AND halves the VGPR cap. A single
// 1024-thread block = 16 waves/CU resident (50%) with VGPR capped at 128 by
// the block-schedulability requirement -- no knob conflict.
__global__ __launch_bounds__(1024)
void k1_grad(const float* __restrict__ X,
             const float* __restrict__ W0, const float* __restrict__ b0,
             const float* __restrict__ W1, const float* __restrict__ b1,
             const float* __restrict__ WV, const float* __restrict__ WQ,
             float* __restrict__ wsPart, int N)
{
  __shared__ __align__(16) unsigned char smem_raw[SMEM_BYTES];
  const int tid = threadIdx.x;
  const int w = tid >> 6, l = tid & 63;
  __bf16* WB = (__bf16*)smem_raw + w*WAVE_REGION_HALFS;

  bf16x8 ones;
  #pragma unroll
  for (int i=0;i<8;++i) ones[i] = (__bf16)1.f;

  f32x4 acc[7] = {};

  const int nb = N >> 6;                 // 64-row batches
  const int tw = K1_BLOCKS*K1_WAVES;     // total waves
  const int gw = blockIdx.x*K1_WAVES + w;
  const int iters = (nb + tw - 1) / tw;

  const int c = l & 15;
  const int r0 = (l>>4)<<3;

  for (int it = 0; it < iters; ++it) {
    const int batch = gw + it*tw;
    const bool active = (batch < nb);

    if (active) {
      const int row = (batch<<6) + l;
      const float* xp = X + (size_t)row*16;
      float x[16];
      {
        const float4* xv = (const float4*)xp;
        float4 t0=xv[0], t1=xv[1], t2=xv[2], t3=xv[3];
        x[0]=t0.x; x[1]=t0.y; x[2]=t0.z; x[3]=t0.w;
        x[4]=t1.x; x[5]=t1.y; x[6]=t1.z; x[7]=t1.w;
        x[8]=t2.x; x[9]=t2.y; x[10]=t2.z; x[11]=t2.w;
        x[12]=t3.x; x[13]=t3.y; x[14]=t3.z; x[15]=t3.w;
      }
      // v = silu(x @ WV^T)
      float vv[16];
      #pragma unroll
      for (int k=0;k<16;++k){
        float s = 0.f;
        #pragma unroll
        for (int d=0;d<16;++d) s = fmaf(x[d], WV[k*16+d], s);
        vv[k] = s * sigmoidf_(s);
      }
      // q = l2norm(silu(x @ WQ^T))   (x dies here)
      float q[16]; float n2 = 0.f;
      #pragma unroll
      for (int k=0;k<16;++k){
        float s = 0.f;
        #pragma unroll
        for (int d=0;d<16;++d) s = fmaf(x[d], WQ[k*16+d], s);
        float t = s * sigmoidf_(s);
        q[k] = t; n2 = fmaf(t, t, n2);
      }
      const float inv = 1.f / fmaxf(sqrtf(n2), 1e-12f);
      #pragma unroll
      for (int k=0;k<16;++k) q[k] *= inv;
      // h = silu(q @ W0^T + b0), keep dsilu
      float h[32], dsh[32];
      #pragma unroll
      for (int j=0;j<32;++j){
        float s = b0[j];
        #pragma unroll
        for (int d=0;d<16;++d) s = fmaf(q[d], W0[j*16+d], s);
        float sg = sigmoidf_(s);
        h[j] = s*sg;
        dsh[j] = sg * fmaf(s, 1.f - sg, 1.f);
      }
      // y, dy (unscaled; scale applied in k2b). vv dies here.
      float dy[16];
      #pragma unroll
      for (int k=0;k<16;++k){
        float s = b1[k];
        #pragma unroll
        for (int j=0;j<32;++j) s = fmaf(h[j], W1[k*32+j], s);
        float sg = sigmoidf_(s);
        float y = s*sg;
        float ds = sg * fmaf(s, 1.f - sg, 1.f);
        dy[k] = (y - vv[k]) * ds;
      }

      // ---- Phase A: [dy|h] staged 32 rows at a time; 2x3 MFMAs ----
      // Same-wave DS in-order (proven by R4's phase overlay): frag reads of
      // sub-phase 1 complete before sub-phase 2's writes land.
      #pragma unroll
      for (int sp=0; sp<2; ++sp){
        const bool mine = (l>>5) == sp;
        if (mine){
          __bf16* R = WB + (l&31)*RREC;
          uint2* p = (uint2*)(R + F_DY);
          #pragma unroll
          for (int k=0;k<16;k+=4) p[k>>2] = make_uint2(pk2_(dy[k],dy[k+1]), pk2_(dy[k+2],dy[k+3]));
          uint2* ph = (uint2*)(R + F_H);
          #pragma unroll
          for (int j=0;j<32;j+=4) ph[j>>2] = make_uint2(pk2_(h[j],h[j+1]), pk2_(h[j+2],h[j+3]));
        }
        const __bf16* base = WB + r0*RREC + c;
        bf16x8 fdy, fh0, fh1;
        #pragma unroll
        for (int i=0;i<8;++i){
          const __bf16* pr = base + i*RREC;
          fdy[i] = pr[F_DY];
          fh0[i] = pr[F_H];
          fh1[i] = pr[F_H + 16];
        }
        acc[0] = __builtin_amdgcn_mfma_f32_16x16x32_bf16(fdy, fh0, acc[0], 0,0,0); // gW1[:, 0:16]
        acc[1] = __builtin_amdgcn_mfma_f32_16x16x32_bf16(fdy, fh1, acc[1], 0,0,0); // gW1[:,16:32]
        acc[2] = __builtin_amdgcn_mfma_f32_16x16x32_bf16(fdy, ones, acc[2], 0,0,0); // gb1
      }

      // dh = (dy @ W1) * dsilu  (dy, dsh die here; h died at staging)
      float dh[32];
      #pragma unroll
      for (int j=0;j<32;++j){
        float s = 0.f;
        #pragma unroll
        for (int k=0;k<16;++k) s = fmaf(dy[k], W1[k*32+j], s);
        dh[j] = s * dsh[j];
      }

      // ---- Phase B: [dh|q] overlays the region; 2x4 MFMAs ----
      #pragma unroll
      for (int sp=0; sp<2; ++sp){
        const bool mine = (l>>5) == sp;
        if (mine){
          __bf16* R = WB + (l&31)*RREC;
          uint2* p = (uint2*)(R + F_DH);
          #pragma unroll
          for (int j=0;j<32;j+=4) p[j>>2] = make_uint2(pk2_(dh[j],dh[j+1]), pk2_(dh[j+2],dh[j+3]));
          uint2* pq = (uint2*)(R + F_Q);
          #pragma unroll
          for (int k=0;k<16;k+=4) pq[k>>2] = make_uint2(pk2_(q[k],q[k+1]), pk2_(q[k+2],q[k+3]));
        }
        const __bf16* base = WB + r0*RREC + c;
        bf16x8 fd0, fd1, fq;
        #pragma unroll
        for (int i=0;i<8;++i){
          const __bf16* pr = base + i*RREC;
          fd0[i] = pr[F_DH];
          fd1[i] = pr[F_DH + 16];
          fq[i]  = pr[F_Q];
        }
        acc[3] = __builtin_amdgcn_mfma_f32_16x16x32_bf16(fd0, fq, acc[3], 0,0,0);   // gW0[0:16, :]
        acc[4] = __builtin_amdgcn_mfma_f32_16x16x32_bf16(fd1, fq, acc[4], 0,0,0);   // gW0[16:32,:]
        acc[5] = __builtin_amdgcn_mfma_f32_16x16x32_bf16(fd0, ones, acc[5], 0,0,0); // gb0[0:16]
        acc[6] = __builtin_amdgcn_mfma_f32_16x16x32_bf16(fd1, ones, acc[6], 0,0,0); // gb0[16:32]
      }
    }
  }

  // ---- block reduction over 16 waves (two-stage, 8 slots x 1792 floats) ----
  __syncthreads();
  float* red = (float*)smem_raw;
  if (w < 8){
    #pragma unroll
    for (int a=0;a<7;++a){
      #pragma unroll
      for (int r=0;r<4;++r)
        red[w*1792 + a*256 + l*4 + r] = acc[a][r];
    }
  }
  __syncthreads();
  if (w >= 8){
    #pragma unroll
    for (int a=0;a<7;++a){
      #pragma unroll
      for (int r=0;r<4;++r)
        red[(w-8)*1792 + a*256 + l*4 + r] += acc[a][r];
    }
  }
  __syncthreads();
  for (int s = tid; s < 1792; s += 1024){
    float sum = 0.f;
    #pragma unroll
    for (int k=0;k<8;++k) sum += red[k*1792 + s];
    wsPart[(size_t)blockIdx.x*1792 + s] = sum;
  }
}

// ---------------- Kernel 2a: partial reduce (512 -> 16 chunks) ----------------
__global__ void k2a_reduce(const float* __restrict__ wsPart, float* __restrict__ tmp)
{
  const int s = blockIdx.x*256 + threadIdx.x;   // 0..1791 (grid.x = 7)
  const int c = blockIdx.y;                     // 0..15
  float g = 0.f;
  #pragma unroll 8
  for (int j=0;j<32;++j) g += wsPart[(size_t)(c*32+j)*1792 + s];
  tmp[(size_t)c*1792 + s] = g;
}

// ---------------- Kernel 2b: final reduce, form updated params ----------------
__global__ void k2b_reduce(const float* __restrict__ tmp,
                           const float* __restrict__ W0, const float* __restrict__ b0,
                           const float* __restrict__ W1, const float* __restrict__ b1,
                           float* __restrict__ P, float scale)
{
  int s = blockIdx.x*256 + threadIdx.x;
  if (s >= 1792) return;
  float g = 0.f;
  #pragma unroll
  for (int c=0;c<16;++c) g += tmp[(size_t)c*1792 + s];
  g *= scale;   // 2/(N*16)
  int a = s >> 8, l = (s >> 2) & 63, r = s & 3;
  int m = ((l>>4)<<2) + r, n = l & 15;
  // P layout (floats): W0[0..511], b0[512..543], W1[544..1055], b1[1056..1071]
  if (a==0)      P[544 + m*32 + n]       = ALPHA*W1[m*32+n]        - THETA*g;
  else if (a==1) P[544 + m*32 + 16 + n]  = ALPHA*W1[m*32+16+n]     - THETA*g;
  else if (a==2){ if (n==0) P[1056 + m]  = ALPHA*b1[m]             - THETA*g; }
  else if (a==3) P[m*16 + n]             = ALPHA*W0[m*16+n]        - THETA*g;
  else if (a==4) P[(16+m)*16 + n]        = ALPHA*W0[(16+m)*16+n]   - THETA*g;
  else if (a==5){ if (n==0) P[512 + m]   = ALPHA*b0[m]             - THETA*g; }
  else           { if (n==0) P[512+16+m] = ALPHA*b0[16+m]          - THETA*g; }
}

// ---------------- Kernel 3: retrieve pass ----------------
__global__ __launch_bounds__(256)
void k3_retrieve(const float* __restrict__ X, const float* __restrict__ WQ,
                 const float* __restrict__ P, float* __restrict__ out, int N)
{
  int row = blockIdx.x*256 + threadIdx.x;
  if (row >= N) return;
  const float* xp = X + (size_t)row*16;
  float x[16];
  {
    const float4* xv = (const float4*)xp;
    float4 t0=xv[0], t1=xv[1], t2=xv[2], t3=xv[3];
    x[0]=t0.x; x[1]=t0.y; x[2]=t0.z; x[3]=t0.w;
    x[4]=t1.x; x[5]=t1.y; x[6]=t1.z; x[7]=t1.w;
    x[8]=t2.x; x[9]=t2.y; x[10]=t2.z; x[11]=t2.w;
    x[12]=t3.x; x[13]=t3.y; x[14]=t3.z; x[15]=t3.w;
  }
  // r = silu(l2norm(x @ WQ^T))   (note: norm BEFORE silu here)
  float rq[16]; float n2 = 0.f;
  #pragma unroll
  for (int k=0;k<16;++k){
    float s = 0.f;
    #pragma unroll
    for (int d=0;d<16;++d) s = fmaf(x[d], WQ[k*16+d], s);
    rq[k] = s; n2 = fmaf(s, s, n2);
  }
  const float inv = 1.f / fmaxf(sqrtf(n2), 1e-12f);
  #pragma unroll
  for (int k=0;k<16;++k){
    float z = rq[k]*inv;
    rq[k] = z * sigmoidf_(z);
  }
  // h = silu(r @ W0'^T + b0')
  float h[32];
  #pragma unroll
  for (int j=0;j<32;++j){
    float s = P[512+j];
    #pragma unroll
    for (int d=0;d<16;++d) s = fmaf(rq[d], P[j*16+d], s);
    h[j] = s * sigmoidf_(s);
  }
  // o = silu(h @ W1'^T + b1')
  float o[16];
  #pragma unroll
  for (int k=0;k<16;++k){
    float s = P[1056+k];
    #pragma unroll
    for (int j=0;j<32;++j) s = fmaf(h[j], P[544 + k*32 + j], s);
    o[k] = s * sigmoidf_(s);
  }
  float4* op = (float4*)(out + (size_t)row*16);
  op[0] = make_float4(o[0],o[1],o[2],o[3]);
  op[1] = make_float4(o[4],o[5],o[6],o[7]);
  op[2] = make_float4(o[8],o[9],o[10],o[11]);
  op[3] = make_float4(o[12],o[13],o[14],o[15]);
}

extern "C" void kernel_launch(void* const* d_in, const int* in_sizes, int n_in,
                              void* d_out, int out_size, void* d_ws, size_t ws_size,
                              hipStream_t stream)
{
  const float* X  = (const float*)d_in[0];
  const float* W0 = (const float*)d_in[1];
  const float* b0 = (const float*)d_in[2];
  const float* W1 = (const float*)d_in[3];
  const float* b1 = (const float*)d_in[4];
  const float* WV = (const float*)d_in[6];
  const float* WQ = (const float*)d_in[7];
  float* ws   = (float*)d_ws;
  float* P    = ws;                         // 1072 floats of updated params
  float* part = ws + 2048;                  // 512*1792 floats of partials
  float* tmp  = part + (size_t)K1_BLOCKS*1792;  // 16*1792 floats

  const int N = in_sizes[0] / 16;
  const float scale = 2.f / (16.f * (float)N);

  k1_grad<<<dim3(K1_BLOCKS), dim3(1024), 0, stream>>>(X, W0, b0, W1, b1, WV, WQ, part, N);
  k2a_reduce<<<dim3(7,16), dim3(256), 0, stream>>>(part, tmp);
  k2b_reduce<<<dim3(7), dim3(256), 0, stream>>>(tmp, W0, b0, W1, b1, P, scale);
  k3_retrieve<<<dim3((N+255)/256), dim3(256), 0, stream>>>(X, WQ, P, (float*)d_out, N);
}